// Round 4
// baseline (56842.297 us; speedup 1.0000x reference)
//
#include <hip/hip_runtime.h>

// ---------------------------------------------------------------------------
// HiPPO-LSTM, B=32, S=2048, D=512, H=512, N=256, G=2048.
//
// Fully-fused sequential kernel (64 persistent blocks, 1 device barrier/step):
//   gates = x_t·Wx^T + h·Whh^T + hippo·Wn^T   (all via bf16 MFMA, split ops:
//     x,h paths: hi/lo Ootomo 3-pass (residual ~1e-5 abs)
//     hippo path: hi/mid/lo 6-pass (residual ~7e-6 abs; hippo ~1000 x w ~0.036)
//   elementwise LSTM in fp64 (c in LDS fp64, double exp)
//   S_f[b] = h·wbar + beta in fp64 (f-clip provably never binds, |f| < ~26)
//   barrier; closed-form fp64 hippo update (A_t/B_t clips never bind):
//     hippo'[b,n] = clip(Sh[b] + (0.5/tp1)(s_n(Sf[b]-prefix_n) - (n+1)hippo[b,n]))
// R1->R3 evidence: error scales ~linearly with per-step gate noise (huge
// Lyapunov amplification); all sources must be <= fp32-rounding level.
// ---------------------------------------------------------------------------

#define B_ 32
#define S_ 2048
#define D_ 512
#define H_ 512
#define NH_ 256
#define G_ 2048
#define KW 2816          // WREC row: hh_hi 512|hh_lo 512|xw_hi 512|xw_lo 512|nw_hi 256|nw_mid 256|nw_lo 256
#define NBLK 64
#define JPB 8
#define MAXS 1000.0

typedef __attribute__((ext_vector_type(8))) short short8;
typedef __attribute__((ext_vector_type(4))) float f32x4;

// ws layout (bytes)
#define CNT_OFF   0ULL
#define SFP_OFF   256ULL                       // double[2][64][32] = 32768
#define HB_OFF    33024ULL                     // ushort[2][32][1024] = 131072 (hi|lo planes)
#define STATE_BYTES 164096ULL
#define XBH_OFF   164096ULL                    // ushort[32][2048][512] = 67108864
#define XBL_OFF   67272960ULL                  // ushort[32][2048][512] = 67108864
#define WREC_OFF  134381824ULL                 // ushort[2048][2816] = 11534336
// total ~145916160 bytes (~139 MiB)

__device__ __forceinline__ unsigned short f2b(float f) {
  unsigned u = __float_as_uint(f);
  unsigned r = (u + 0x7fffu + ((u >> 16) & 1u)) >> 16;
  return (unsigned short)r;
}
__device__ __forceinline__ float b2f(unsigned short s) {
  return __uint_as_float(((unsigned)s) << 16);
}
__device__ __forceinline__ double sigm_d(double x) { return 1.0 / (1.0 + exp(-x)); }
__device__ __forceinline__ double tanh_d(double x) {
  double e = exp(2.0 * x);
  return isinf(e) ? 1.0 : (1.0 - 2.0 / (e + 1.0));
}

// ---------------- prep kernels ----------------
__global__ __launch_bounds__(256) void k_cvt2(const float* __restrict__ in,
                                              unsigned short* __restrict__ hi,
                                              unsigned short* __restrict__ lo, size_t n) {
  size_t i = (size_t)blockIdx.x * blockDim.x + threadIdx.x;
  size_t stride = (size_t)gridDim.x * blockDim.x;
  for (; i < n; i += stride) {
    float v = in[i];
    unsigned short h = f2b(v);
    hi[i] = h;
    lo[i] = f2b(v - b2f(h));
  }
}

__global__ __launch_bounds__(256) void k_wrec2(const float* __restrict__ Whh,
                                               const float* __restrict__ Wih,
                                               unsigned short* __restrict__ out) {
  size_t i = (size_t)blockIdx.x * 256 + threadIdx.x;   // over 2048*2816
  if (i >= (size_t)G_ * KW) return;
  int gb = (int)(i / KW), k = (int)(i % KW);
  int blk = gb >> 5, c = gb & 31;
  int grow = (c >> 3) * H_ + blk * JPB + (c & 7);      // gate*512 + hidden index
  unsigned short v;
  if (k < 512) {                                        // Whh hi
    v = f2b(Whh[(size_t)grow * 512 + k]);
  } else if (k < 1024) {                                // Whh lo
    float w = Whh[(size_t)grow * 512 + (k - 512)];
    v = f2b(w - b2f(f2b(w)));
  } else if (k < 1536) {                                // Wih-x hi
    v = f2b(Wih[(size_t)grow * 768 + (k - 1024)]);
  } else if (k < 2048) {                                // Wih-x lo
    float w = Wih[(size_t)grow * 768 + (k - 1536)];
    v = f2b(w - b2f(f2b(w)));
  } else if (k < 2304) {                                // Wih-hippo hi
    v = f2b(Wih[(size_t)grow * 768 + 512 + (k - 2048)]);
  } else if (k < 2560) {                                // Wih-hippo mid
    float w = Wih[(size_t)grow * 768 + 512 + (k - 2304)];
    v = f2b(w - b2f(f2b(w)));
  } else {                                              // Wih-hippo lo
    float w = Wih[(size_t)grow * 768 + 512 + (k - 2560)];
    float h1 = b2f(f2b(w));
    float m1 = b2f(f2b(w - h1));
    v = f2b(w - h1 - m1);
  }
  out[i] = v;
}

// ---------------- persistent sequential kernel ----------------
__global__ __launch_bounds__(256, 1) void k_seq(const unsigned short* __restrict__ XBH,
                                                const unsigned short* __restrict__ XBL,
                                                const unsigned short* __restrict__ WREC,
                                                const float* __restrict__ Wh2h,
                                                const float* __restrict__ bh2h,
                                                const float* __restrict__ bih,
                                                const float* __restrict__ bhh,
                                                float* __restrict__ out,
                                                unsigned short* __restrict__ HB,
                                                double* __restrict__ SfP,
                                                unsigned* __restrict__ cnt) {
  const int blk = blockIdx.x, tid = threadIdx.x;

  __shared__ double hip_d[32][257];            // fp64 hippo state (padded)
  __shared__ unsigned short hip_hi[32][264];   // bf16 hi/mid/lo for MFMA A-frags
  __shared__ unsigned short hip_mi[32][264];
  __shared__ unsigned short hip_lo[32][264];
  __shared__ float gat_xh[32][33];             // x+h MFMA partial
  __shared__ float gat_n[32][33];              // hippo MFMA partial
  __shared__ double cst[32][JPB];              // cell state fp64
  __shared__ double segw[32][8], segu[32][8];
  __shared__ double sfl[32];
  __shared__ double wbar[JPB];
  __shared__ double stabd[256];
  __shared__ double sbeta;

  for (int i = tid; i < 32 * 257; i += 256) (&hip_d[0][0])[i] = 0.0;
  for (int i = tid; i < 32 * 264; i += 256) {
    (&hip_hi[0][0])[i] = 0; (&hip_mi[0][0])[i] = 0; (&hip_lo[0][0])[i] = 0;
  }
  for (int i = tid; i < 32 * JPB; i += 256) (&cst[0][0])[i] = 0.0;
  if (tid < 256) stabd[tid] = sqrt(2.0 * (double)tid + 1.0);
  if (tid < JPB) {
    double s = 0.0;
    for (int n = 0; n < NH_; ++n) s += (double)Wh2h[(size_t)n * H_ + blk * JPB + tid];
    wbar[tid] = s;
  }
  if (tid == 0) {
    double s = 0.0;
    for (int n = 0; n < NH_; ++n) s += (double)bh2h[n];
    sbeta = s;
  }
  __syncthreads();

  // MFMA roles (4 waves)
  const int w = tid >> 6, l = tid & 63;
  const int lb = l & 15, lq = l >> 4;
  const int mt = w & 1, nt = w >> 1;
  const int bA = mt * 16 + lb;         // batch row for A frags
  const int cB = nt * 16 + lb;         // local gate col for B frags
  const unsigned short* wrow = WREC + ((size_t)(blk * 32 + cB)) * KW + lq * 8;
  // elementwise roles
  const int eb = tid >> 3, ej = tid & 7;
  const int jg = blk * JPB + ej;
  // per-thread gate biases (fp64)
  const double bi0 = (double)bih[0 * 512 + jg] + (double)bhh[0 * 512 + jg];
  const double bi1 = (double)bih[1 * 512 + jg] + (double)bhh[1 * 512 + jg];
  const double bi2 = (double)bih[2 * 512 + jg] + (double)bhh[2 * 512 + jg];
  const double bi3 = (double)bih[3 * 512 + jg] + (double)bhh[3 * 512 + jg];
  // hippo-scan roles
  const int hb = tid & 31, hs = tid >> 5;

  for (int t = 0; t < S_; ++t) {
    const int wslot = t & 1, rslot = wslot ^ 1;

    // ---- gates MFMA ----
    // hippo path: hi/mid/lo x hi/mid/lo, 6 passes, K=256 (separate accumulator)
    f32x4 an = {0.f, 0.f, 0.f, 0.f};
#pragma unroll
    for (int kt = 0; kt < 8; ++kt) {
      short8 ah = *(const short8*)(&hip_hi[bA][kt * 32 + lq * 8]);
      short8 am = *(const short8*)(&hip_mi[bA][kt * 32 + lq * 8]);
      short8 al = *(const short8*)(&hip_lo[bA][kt * 32 + lq * 8]);
      short8 bh = *(const short8*)(wrow + 2048 + kt * 32);
      short8 bm = *(const short8*)(wrow + 2304 + kt * 32);
      short8 bl = *(const short8*)(wrow + 2560 + kt * 32);
      an = __builtin_amdgcn_mfma_f32_16x16x32_bf16(ah, bh, an, 0, 0, 0);
      an = __builtin_amdgcn_mfma_f32_16x16x32_bf16(ah, bm, an, 0, 0, 0);
      an = __builtin_amdgcn_mfma_f32_16x16x32_bf16(am, bh, an, 0, 0, 0);
      an = __builtin_amdgcn_mfma_f32_16x16x32_bf16(ah, bl, an, 0, 0, 0);
      an = __builtin_amdgcn_mfma_f32_16x16x32_bf16(am, bm, an, 0, 0, 0);
      an = __builtin_amdgcn_mfma_f32_16x16x32_bf16(al, bh, an, 0, 0, 0);
    }
    // h path: hi/lo Ootomo 3-pass, K=512 (h from global double-buffer)
    f32x4 axh = {0.f, 0.f, 0.f, 0.f};
    const unsigned short* hrow = HB + (size_t)rslot * (B_ * 1024) + (size_t)bA * 1024 + lq * 8;
#pragma unroll
    for (int kt = 0; kt < 16; ++kt) {
      short8 ah = *(const short8*)(hrow + kt * 32);
      short8 al = *(const short8*)(hrow + 512 + kt * 32);
      short8 bh = *(const short8*)(wrow + kt * 32);
      short8 bl = *(const short8*)(wrow + 512 + kt * 32);
      axh = __builtin_amdgcn_mfma_f32_16x16x32_bf16(ah, bh, axh, 0, 0, 0);
      axh = __builtin_amdgcn_mfma_f32_16x16x32_bf16(ah, bl, axh, 0, 0, 0);
      axh = __builtin_amdgcn_mfma_f32_16x16x32_bf16(al, bh, axh, 0, 0, 0);
    }
    // x path: hi/lo Ootomo 3-pass, K=512
    const unsigned short* xh = XBH + ((size_t)bA * S_ + t) * D_ + lq * 8;
    const unsigned short* xl = XBL + ((size_t)bA * S_ + t) * D_ + lq * 8;
#pragma unroll
    for (int kt = 0; kt < 16; ++kt) {
      short8 ah = *(const short8*)(xh + kt * 32);
      short8 al = *(const short8*)(xl + kt * 32);
      short8 bh = *(const short8*)(wrow + 1024 + kt * 32);
      short8 bl = *(const short8*)(wrow + 1536 + kt * 32);
      axh = __builtin_amdgcn_mfma_f32_16x16x32_bf16(ah, bh, axh, 0, 0, 0);
      axh = __builtin_amdgcn_mfma_f32_16x16x32_bf16(ah, bl, axh, 0, 0, 0);
      axh = __builtin_amdgcn_mfma_f32_16x16x32_bf16(al, bh, axh, 0, 0, 0);
    }
#pragma unroll
    for (int r = 0; r < 4; ++r) {
      gat_xh[mt * 16 + lq * 4 + r][cB] = axh[r];
      gat_n[mt * 16 + lq * 4 + r][cB] = an[r];
    }
    __syncthreads();

    // ---- elementwise LSTM (fp64) ----
    {
      double pi = (double)gat_xh[eb][0 * 8 + ej] + (double)gat_n[eb][0 * 8 + ej] + bi0;
      double pf = (double)gat_xh[eb][1 * 8 + ej] + (double)gat_n[eb][1 * 8 + ej] + bi1;
      double pg = (double)gat_xh[eb][2 * 8 + ej] + (double)gat_n[eb][2 * 8 + ej] + bi2;
      double po = (double)gat_xh[eb][3 * 8 + ej] + (double)gat_n[eb][3 * 8 + ej] + bi3;
      double c = sigm_d(pf) * cst[eb][ej] + sigm_d(pi) * tanh_d(pg);
      cst[eb][ej] = c;
      double h = sigm_d(po) * tanh_d(c);
      size_t oidx = (size_t)eb * (S_ * H_) + (size_t)t * H_ + jg;
      out[oidx] = (float)h;
      out[(size_t)B_ * S_ * H_ + oidx] = (float)c;
      float hf = (float)h;
      unsigned short hh = f2b(hf);
      unsigned short hl = f2b((float)(h - (double)b2f(hh)));
      unsigned short* hb_w = HB + (size_t)wslot * (B_ * 1024) + (size_t)eb * 1024;
      hb_w[jg] = hh;
      hb_w[512 + jg] = hl;
      // partial S_f (fp64)
      double part = h * wbar[ej];
      part += __shfl_down(part, 4, 64);
      part += __shfl_down(part, 2, 64);
      part += __shfl_down(part, 1, 64);
      if (ej == 0) SfP[(size_t)wslot * (NBLK * B_) + blk * B_ + eb] = part;
    }
    __syncthreads();   // drains vmem before barrier arrival

    if (t == S_ - 1) break;

    // -------- device barrier (single monotonic counter) --------
    if (tid == 0) {
      __hip_atomic_fetch_add(cnt, 1u, __ATOMIC_RELEASE, __HIP_MEMORY_SCOPE_AGENT);
      const unsigned target = (unsigned)NBLK * (unsigned)(t + 1);
      while (__hip_atomic_load(cnt, __ATOMIC_RELAXED, __HIP_MEMORY_SCOPE_AGENT) < target) {}
      __threadfence();  // acquire: invalidate caches
    }
    __syncthreads();

    // S_f reduce (fp64) + hippo segment sums (fp64)
    {
      const double* sp = SfP + (size_t)wslot * (NBLK * B_) + eb;
      double v = 0.0;
#pragma unroll
      for (int m = 0; m < 8; ++m) v += sp[(ej * 8 + m) * B_];
      v += __shfl_down(v, 4, 64);
      v += __shfl_down(v, 2, 64);
      v += __shfl_down(v, 1, 64);
      if (ej == 0) sfl[eb] = v + sbeta;

      double sw = 0.0, su = 0.0;
#pragma unroll 4
      for (int i = 0; i < 32; ++i) {
        double hv = hip_d[hb][hs * 32 + i];
        sw += stabd[hs * 32 + i] * hv;
        su += hv;
      }
      segw[hb][hs] = sw;
      segu[hb][hs] = su;
    }
    __syncthreads();

    // hippo closed-form update in fp64 (redundant per block, deterministic)
    {
      double U = 0.0, Sh = 0.0;
#pragma unroll
      for (int s2 = 0; s2 < 8; ++s2) {
        Sh += segu[hb][s2];
        if (s2 < hs) U += segw[hb][s2];
      }
      const double Sf = sfl[hb];
      const double inv = 0.5 / (double)(t + 1);
      for (int i = 0; i < 32; ++i) {
        int n = hs * 32 + i;
        double hn = hip_d[hb][n];
        double v = Sh + inv * (stabd[n] * (Sf - U) - (double)(n + 1) * hn);
        v = fmin(fmax(v, -MAXS), MAXS);
        hip_d[hb][n] = v;
        unsigned short vh = f2b((float)v);
        double rem = v - (double)b2f(vh);
        unsigned short vm = f2b((float)rem);
        rem -= (double)b2f(vm);
        hip_hi[hb][n] = vh;
        hip_mi[hb][n] = vm;
        hip_lo[hb][n] = f2b((float)rem);
        U += stabd[n] * hn;
      }
    }
    __syncthreads();
  }
}

extern "C" void kernel_launch(void* const* d_in, const int* in_sizes, int n_in,
                              void* d_out, int out_size, void* d_ws, size_t ws_size,
                              hipStream_t stream) {
  const float* x    = (const float*)d_in[0];
  const float* Wih  = (const float*)d_in[1];
  const float* Whh  = (const float*)d_in[2];
  const float* bih  = (const float*)d_in[3];
  const float* bhh  = (const float*)d_in[4];
  const float* Wh2h = (const float*)d_in[5];
  const float* bh2h = (const float*)d_in[6];
  float* out = (float*)d_out;
  char* ws = (char*)d_ws;

  unsigned* cnt        = (unsigned*)(ws + CNT_OFF);
  double* SfP          = (double*)(ws + SFP_OFF);
  unsigned short* HB   = (unsigned short*)(ws + HB_OFF);
  unsigned short* XBH  = (unsigned short*)(ws + XBH_OFF);
  unsigned short* XBL  = (unsigned short*)(ws + XBL_OFF);
  unsigned short* WREC = (unsigned short*)(ws + WREC_OFF);

  hipMemsetAsync(ws, 0, STATE_BYTES, stream);
  k_cvt2<<<8192, 256, 0, stream>>>(x, XBH, XBL, (size_t)B_ * S_ * D_);
  k_wrec2<<<((size_t)G_ * KW + 255) / 256, 256, 0, stream>>>(Whh, Wih, WREC);
  k_seq<<<NBLK, 256, 0, stream>>>(XBH, XBL, WREC, Wh2h, bh2h, bih, bhh, out, HB, SfP, cnt);
}